// Round 6
// baseline (571.374 us; speedup 1.0000x reference)
//
#include <hip/hip_runtime.h>
#include <math.h>

#define NB 16
#define NS 1024
#define ND 768
#define NH 12
#define NDH 64

static constexpr size_t QKV_ELEMS = (size_t)NB * NH * NS * NDH;  // 12.58M elems
static constexpr float QSCALE = 0.125f * 1.44269504088896f;      // 1/sqrt(64) * log2(e)

typedef __attribute__((ext_vector_type(8))) _Float16 half8;   // MFMA A/B frag
typedef __attribute__((ext_vector_type(4))) float f32x4;      // MFMA C/D frag

// ---------------------------------------------------------------------------
// Kernel 1: QKV projection via fp16 MFMA (x split hi/lo for near-fp32 accuracy).
//   x: [B*S, 768] fp32. W*: [H, 64, 64] (out,in). b*: [H, 64].
//   Outputs: q,k fp16 [bh, s, d] (q pre-scaled), vT fp16 [bh, d, s] computed
//   DIRECTLY transposed via swapped MFMA operands (D[d][token] = Wv . x^T).
// grid (128 token-tiles, 12 heads), block 256 = 4 waves x 32 tokens.
// ---------------------------------------------------------------------------
__device__ __forceinline__ void proj_one(
    const float* __restrict__ W, int h, int l16, int lg,
    const half8 xh[2][2], const half8 xl[2][2], f32x4 acc[2][4])
{
    #pragma unroll
    for (int n = 0; n < 4; ++n)
        #pragma unroll
        for (int kc = 0; kc < 2; ++kc) {
            const float* pw = W + (size_t)(h * NDH + n * 16 + l16) * NDH + kc * 32 + lg * 8;
            const float4 a = *reinterpret_cast<const float4*>(pw);
            const float4 b = *reinterpret_cast<const float4*>(pw + 4);
            const float wv[8] = {a.x, a.y, a.z, a.w, b.x, b.y, b.z, b.w};
            half8 wf;
            #pragma unroll
            for (int j = 0; j < 8; ++j) wf[j] = (_Float16)wv[j];
            #pragma unroll
            for (int m = 0; m < 2; ++m) {
                acc[m][n] = __builtin_amdgcn_mfma_f32_16x16x32_f16(xh[m][kc], wf, acc[m][n], 0, 0, 0);
                acc[m][n] = __builtin_amdgcn_mfma_f32_16x16x32_f16(xl[m][kc], wf, acc[m][n], 0, 0, 0);
            }
        }
}

__global__ __launch_bounds__(256) void qkv_mfma(
    const float* __restrict__ x,
    const float* __restrict__ Wq, const float* __restrict__ bq,
    const float* __restrict__ Wk, const float* __restrict__ bk,
    const float* __restrict__ Wv, const float* __restrict__ bv,
    _Float16* __restrict__ qo, _Float16* __restrict__ ko, _Float16* __restrict__ vT)
{
    const int tb = blockIdx.x;            // 0..127
    const int h  = blockIdx.y;            // 0..11
    const int t  = threadIdx.x;
    const int w  = t >> 6;
    const int l  = t & 63;
    const int l16 = l & 15, lg = l >> 4;
    const int tok0 = tb * 128 + w * 32;   // wave's 32 tokens (same batch)
    const int b  = tok0 >> 10;
    const int s0 = tok0 & 1023;
    const int bh = b * NH + h;

    // A-frags: x hi/lo fp16. lane: row=l16 (token), k=lg*8+j (d). Note this
    // layout is ALSO the valid B-frag layout (col=l16, k=lg*8+j) for V-swap.
    half8 xh[2][2], xl[2][2];
    #pragma unroll
    for (int m = 0; m < 2; ++m)
        #pragma unroll
        for (int kc = 0; kc < 2; ++kc) {
            const float* px = x + (size_t)(tok0 + m * 16 + l16) * ND + h * NDH + kc * 32 + lg * 8;
            const float4 a = *reinterpret_cast<const float4*>(px);
            const float4 c = *reinterpret_cast<const float4*>(px + 4);
            const float vv[8] = {a.x, a.y, a.z, a.w, c.x, c.y, c.z, c.w};
            #pragma unroll
            for (int j = 0; j < 8; ++j) {
                const _Float16 hi = (_Float16)vv[j];
                xh[m][kc][j] = hi;
                xl[m][kc][j] = (_Float16)(vv[j] - (float)hi);
            }
        }

    f32x4 acc[2][4];

    // ---- Q
    #pragma unroll
    for (int m = 0; m < 2; ++m)
        #pragma unroll
        for (int n = 0; n < 4; ++n) acc[m][n] = f32x4{0.f, 0.f, 0.f, 0.f};
    proj_one(Wq, h, l16, lg, xh, xl, acc);
    #pragma unroll
    for (int n = 0; n < 4; ++n) {
        const float bb = bq[h * NDH + n * 16 + l16];
        #pragma unroll
        for (int m = 0; m < 2; ++m)
            #pragma unroll
            for (int r = 0; r < 4; ++r)
                qo[((size_t)bh * NS + s0 + m * 16 + lg * 4 + r) * NDH + n * 16 + l16] =
                    (_Float16)((acc[m][n][r] + bb) * QSCALE);
    }

    // ---- K
    #pragma unroll
    for (int m = 0; m < 2; ++m)
        #pragma unroll
        for (int n = 0; n < 4; ++n) acc[m][n] = f32x4{0.f, 0.f, 0.f, 0.f};
    proj_one(Wk, h, l16, lg, xh, xl, acc);
    #pragma unroll
    for (int n = 0; n < 4; ++n) {
        const float bb = bk[h * NDH + n * 16 + l16];
        #pragma unroll
        for (int m = 0; m < 2; ++m)
            #pragma unroll
            for (int r = 0; r < 4; ++r)
                ko[((size_t)bh * NS + s0 + m * 16 + lg * 4 + r) * NDH + n * 16 + l16] =
                    (_Float16)(acc[m][n][r] + bb);
    }

    // ---- V, swapped: D[d][token] = Wv . x^T  -> writes vT[bh][d][s] with the
    //      same 4x32B-txn store pattern as Q/K (no 2B scatter).
    f32x4 accT[4][2];
    #pragma unroll
    for (int dt = 0; dt < 4; ++dt)
        #pragma unroll
        for (int tt = 0; tt < 2; ++tt) accT[dt][tt] = f32x4{0.f, 0.f, 0.f, 0.f};
    #pragma unroll
    for (int dt = 0; dt < 4; ++dt)
        #pragma unroll
        for (int kc = 0; kc < 2; ++kc) {
            const float* pw = Wv + (size_t)(h * NDH + dt * 16 + l16) * NDH + kc * 32 + lg * 8;
            const float4 a = *reinterpret_cast<const float4*>(pw);
            const float4 b = *reinterpret_cast<const float4*>(pw + 4);
            const float wv[8] = {a.x, a.y, a.z, a.w, b.x, b.y, b.z, b.w};
            half8 wf;
            #pragma unroll
            for (int j = 0; j < 8; ++j) wf[j] = (_Float16)wv[j];
            #pragma unroll
            for (int tt = 0; tt < 2; ++tt) {
                accT[dt][tt] = __builtin_amdgcn_mfma_f32_16x16x32_f16(wf, xh[tt][kc], accT[dt][tt], 0, 0, 0);
                accT[dt][tt] = __builtin_amdgcn_mfma_f32_16x16x32_f16(wf, xl[tt][kc], accT[dt][tt], 0, 0, 0);
            }
        }
    #pragma unroll
    for (int dt = 0; dt < 4; ++dt)
        #pragma unroll
        for (int r = 0; r < 4; ++r) {
            const float bb = bv[h * NDH + dt * 16 + lg * 4 + r];
            #pragma unroll
            for (int tt = 0; tt < 2; ++tt)
                vT[((size_t)bh * NDH + dt * 16 + lg * 4 + r) * NS + s0 + tt * 16 + l16] =
                    (_Float16)(accT[dt][tt][r] + bb);
        }
}

// ---------------------------------------------------------------------------
// Kernel 2: barrier-free MFMA flash attention. Block = 4 INDEPENDENT waves
// (each: 32 q-rows, own PT slice -> no __syncthreads anywhere). KV-tile 64,
// 16 iterations. K/Q/V fragments loaded directly from global (L1/L2-hot).
// Swapped QK^T (S^T = K*Q^T) -> softmax mostly in-lane (2 shfl per stat).
// P crosses lanes via row-XOR-swizzled per-wave LDS (same-wave ordering).
// ---------------------------------------------------------------------------
__global__ __launch_bounds__(256, 4) void flash_mfma(
    const _Float16* __restrict__ q, const _Float16* __restrict__ k,
    const _Float16* __restrict__ vT, float* __restrict__ out)
{
    __shared__ __align__(16) _Float16 PT[4][32 * 64];  // per-wave [q][kv], swizzled

    const int bh = blockIdx.x;            // 0..191; XCD = bh%8 fixed (192%8==0)
    const int qt = blockIdx.y;            // 0..7
    const int t  = threadIdx.x;
    const int w  = t >> 6;
    const int l  = t & 63;
    const int l16 = l & 15, lg = l >> 4;
    const int q0 = qt * 128 + w * 32;

    const size_t qkbase = (size_t)bh * NS * NDH;
    const size_t vtbase = (size_t)bh * NDH * NS;

    // Q B-frags (loop-invariant): lane: col=l16 (q), k=lg*8+j (d)
    half8 qf[2][2];
    #pragma unroll
    for (int n2 = 0; n2 < 2; ++n2)
        #pragma unroll
        for (int kc = 0; kc < 2; ++kc)
            qf[n2][kc] = *reinterpret_cast<const half8*>(
                q + qkbase + (size_t)(q0 + n2 * 16 + l16) * NDH + kc * 32 + lg * 8);

    f32x4 Oacc[2][4];
    #pragma unroll
    for (int m = 0; m < 2; ++m)
        #pragma unroll
        for (int n = 0; n < 4; ++n) Oacc[m][n] = f32x4{0.f, 0.f, 0.f, 0.f};
    float mi[2] = {-INFINITY, -INFINITY};
    float li[2] = {0.f, 0.f};

    // K A-frag prefetch for kt=0: lane: row=l16 (kv), k=lg*8+j (d)
    half8 kf[4][2];
    #pragma unroll
    for (int m4 = 0; m4 < 4; ++m4)
        #pragma unroll
        for (int kc = 0; kc < 2; ++kc)
            kf[m4][kc] = *reinterpret_cast<const half8*>(
                k + qkbase + (size_t)(m4 * 16 + l16) * NDH + kc * 32 + lg * 8);

    for (int kt = 0; kt < 16; ++kt) {
        const int kvb = kt * 64;

        // ---- issue V B-frags early (used after softmax): lane: col=l16 (d), k=lg*8+j (kv)
        half8 vf[4][2];
        #pragma unroll
        for (int n4 = 0; n4 < 4; ++n4)
            #pragma unroll
            for (int kc = 0; kc < 2; ++kc)
                vf[n4][kc] = *reinterpret_cast<const half8*>(
                    vT + vtbase + (size_t)(n4 * 16 + l16) * NS + kvb + kc * 32 + lg * 8);

        // ---- S^T = K * Q^T : st[m4][n2], elem r -> kv = m4*16+lg*4+r, q = n2*16+l16
        f32x4 st[4][2];
        __builtin_amdgcn_s_setprio(1);
        #pragma unroll
        for (int m4 = 0; m4 < 4; ++m4)
            #pragma unroll
            for (int n2 = 0; n2 < 2; ++n2) {
                st[m4][n2] = f32x4{0.f, 0.f, 0.f, 0.f};
                #pragma unroll
                for (int kc = 0; kc < 2; ++kc)
                    st[m4][n2] = __builtin_amdgcn_mfma_f32_16x16x32_f16(
                        kf[m4][kc], qf[n2][kc], st[m4][n2], 0, 0, 0);
            }
        __builtin_amdgcn_s_setprio(0);

        // ---- prefetch K for kt+1 (latency covered by softmax+PV)
        half8 kf2[4][2];
        if (kt < 15) {
            #pragma unroll
            for (int m4 = 0; m4 < 4; ++m4)
                #pragma unroll
                for (int kc = 0; kc < 2; ++kc)
                    kf2[m4][kc] = *reinterpret_cast<const half8*>(
                        k + qkbase + (size_t)(kvb + 64 + m4 * 16 + l16) * NDH + kc * 32 + lg * 8);
        }

        // ---- online softmax in exp2 domain (scale folded into q)
        float cfac[2];
        #pragma unroll
        for (int n2 = 0; n2 < 2; ++n2) {
            float pm = st[0][n2][0];
            #pragma unroll
            for (int m4 = 0; m4 < 4; ++m4)
                #pragma unroll
                for (int r = 0; r < 4; ++r) pm = fmaxf(pm, st[m4][n2][r]);
            pm = fmaxf(pm, __shfl_xor(pm, 16));
            pm = fmaxf(pm, __shfl_xor(pm, 32));
            const float mn = fmaxf(mi[n2], pm);
            cfac[n2] = __builtin_amdgcn_exp2f(mi[n2] - mn);
            mi[n2] = mn;
            float rs = 0.f;
            #pragma unroll
            for (int m4 = 0; m4 < 4; ++m4)
                #pragma unroll
                for (int r = 0; r < 4; ++r) {
                    const float p = __builtin_amdgcn_exp2f(st[m4][n2][r] - mn);
                    st[m4][n2][r] = p;
                    rs += p;
                }
            rs += __shfl_xor(rs, 16);
            rs += __shfl_xor(rs, 32);
            li[n2] = li[n2] * cfac[n2] + rs;
        }

        // ---- rescale Oacc BEFORE adding this tile's PV
        #pragma unroll
        for (int m2 = 0; m2 < 2; ++m2) {
            float cb[4];
            #pragma unroll
            for (int r = 0; r < 4; ++r) cb[r] = __shfl(cfac[m2], lg * 4 + r);
            #pragma unroll
            for (int n4 = 0; n4 < 4; ++n4)
                #pragma unroll
                for (int r = 0; r < 4; ++r) Oacc[m2][n4][r] *= cb[r];
        }

        // ---- P -> per-wave PT (packed fp16, b64 writes, 16B-slot XOR swizzle)
        _Float16* Pw = PT[w];
        #pragma unroll
        for (int n2 = 0; n2 < 2; ++n2) {
            const int row = n2 * 16 + l16;
            #pragma unroll
            for (int m4 = 0; m4 < 4; ++m4) {
                const unsigned int p01 = __builtin_bit_cast(unsigned int,
                    __builtin_amdgcn_cvt_pkrtz(st[m4][n2][0], st[m4][n2][1]));
                const unsigned int p23 = __builtin_bit_cast(unsigned int,
                    __builtin_amdgcn_cvt_pkrtz(st[m4][n2][2], st[m4][n2][3]));
                const int swz = (m4 * 2 + (lg >> 1)) ^ (row & 7);   // 16B slot index
                uint2* dst = reinterpret_cast<uint2*>(&Pw[row * 64 + swz * 8 + (lg & 1) * 4]);
                *dst = uint2{p01, p23};
            }
        }

        // ---- P A-frags: row = m2*16+l16 (q), k = kv = kc*32+lg*8+j
        half8 pf[2][2];
        #pragma unroll
        for (int m2 = 0; m2 < 2; ++m2) {
            const int row = m2 * 16 + l16;
            #pragma unroll
            for (int kc = 0; kc < 2; ++kc) {
                const int swz = (kc * 4 + lg) ^ (row & 7);
                pf[m2][kc] = *reinterpret_cast<const half8*>(&Pw[row * 64 + swz * 8]);
            }
        }

        // ---- PV accumulate
        __builtin_amdgcn_s_setprio(1);
        #pragma unroll
        for (int m2 = 0; m2 < 2; ++m2)
            #pragma unroll
            for (int n4 = 0; n4 < 4; ++n4)
                #pragma unroll
                for (int kc = 0; kc < 2; ++kc)
                    Oacc[m2][n4] = __builtin_amdgcn_mfma_f32_16x16x32_f16(
                        pf[m2][kc], vf[n4][kc], Oacc[m2][n4], 0, 0, 0);
        __builtin_amdgcn_s_setprio(0);

        // rotate prefetched K
        #pragma unroll
        for (int m4 = 0; m4 < 4; ++m4)
            #pragma unroll
            for (int kc = 0; kc < 2; ++kc) kf[m4][kc] = kf2[m4][kc];
    }

    // ---- epilogue
    const int b = bh / NH;
    const int h = bh % NH;
    float inv[2] = {1.f / li[0], 1.f / li[1]};
    #pragma unroll
    for (int m2 = 0; m2 < 2; ++m2)
        #pragma unroll
        for (int r = 0; r < 4; ++r) {
            const float ib = __shfl(inv[m2], lg * 4 + r);
            const int s = q0 + m2 * 16 + lg * 4 + r;
            #pragma unroll
            for (int n4 = 0; n4 < 4; ++n4)
                out[((size_t)b * NS + s) * ND + h * NDH + n4 * 16 + l16] = Oacc[m2][n4][r] * ib;
        }
}

// ---------------------------------------------------------------------------
extern "C" void kernel_launch(void* const* d_in, const int* in_sizes, int n_in,
                              void* d_out, int out_size, void* d_ws, size_t ws_size,
                              hipStream_t stream)
{
    const float* x  = (const float*)d_in[0];
    const float* Wq = (const float*)d_in[1];
    const float* bq = (const float*)d_in[2];
    const float* Wk = (const float*)d_in[3];
    const float* bk = (const float*)d_in[4];
    const float* Wv = (const float*)d_in[5];
    const float* bv = (const float*)d_in[6];
    float* out = (float*)d_out;

    _Float16* qb = (_Float16*)d_ws;
    _Float16* kb = qb + QKV_ELEMS;
    _Float16* vt = kb + QKV_ELEMS;

    dim3 g1(NB * NS / 128, NH);
    qkv_mfma<<<g1, 256, 0, stream>>>(x, Wq, bq, Wk, bk, Wv, bv, qb, kb, vt);

    dim3 g2(NB * NH, 8);   // x = bh (pins each head to one XCD), y = q-tile
    flash_mfma<<<g2, 256, 0, stream>>>(qb, kb, vt, out);
}

// Round 8
// 320.241 us; speedup vs baseline: 1.7842x; 1.7842x over previous
//
#include <hip/hip_runtime.h>
#include <math.h>

#define NB 16
#define NS 1024
#define ND 768
#define NH 12
#define NDH 64

static constexpr size_t QKV_ELEMS = (size_t)NB * NH * NS * NDH;  // 12.58M elems
static constexpr float QSCALE = 0.125f * 1.44269504088896f;      // 1/sqrt(64) * log2(e)

typedef __attribute__((ext_vector_type(8))) _Float16 half8;   // MFMA A/B frag
typedef __attribute__((ext_vector_type(4))) float f32x4;      // MFMA C/D frag

// ---------------------------------------------------------------------------
// Kernel 1: QKV projection via fp16 MFMA (x split hi/lo for near-fp32 accuracy).
//   x: [B*S, 768] fp32. W*: [H, 64, 64] (out,in). b*: [H, 64].
//   Outputs: q,k fp16 [bh, s, d] (q pre-scaled), vT fp16 [bh, d, s] computed
//   DIRECTLY transposed via swapped MFMA operands (D[d][token] = Wv . x^T).
// grid (128 token-tiles, 12 heads), block 256 = 4 waves x 32 tokens.
// ---------------------------------------------------------------------------
__device__ __forceinline__ void proj_one(
    const float* __restrict__ W, int h, int l16, int lg,
    const half8 xh[2][2], const half8 xl[2][2], f32x4 acc[2][4])
{
    #pragma unroll
    for (int n = 0; n < 4; ++n)
        #pragma unroll
        for (int kc = 0; kc < 2; ++kc) {
            const float* pw = W + (size_t)(h * NDH + n * 16 + l16) * NDH + kc * 32 + lg * 8;
            const float4 a = *reinterpret_cast<const float4*>(pw);
            const float4 b = *reinterpret_cast<const float4*>(pw + 4);
            const float wv[8] = {a.x, a.y, a.z, a.w, b.x, b.y, b.z, b.w};
            half8 wf;
            #pragma unroll
            for (int j = 0; j < 8; ++j) wf[j] = (_Float16)wv[j];
            #pragma unroll
            for (int m = 0; m < 2; ++m) {
                acc[m][n] = __builtin_amdgcn_mfma_f32_16x16x32_f16(xh[m][kc], wf, acc[m][n], 0, 0, 0);
                acc[m][n] = __builtin_amdgcn_mfma_f32_16x16x32_f16(xl[m][kc], wf, acc[m][n], 0, 0, 0);
            }
        }
}

__global__ __launch_bounds__(256) void qkv_mfma(
    const float* __restrict__ x,
    const float* __restrict__ Wq, const float* __restrict__ bq,
    const float* __restrict__ Wk, const float* __restrict__ bk,
    const float* __restrict__ Wv, const float* __restrict__ bv,
    _Float16* __restrict__ qo, _Float16* __restrict__ ko, _Float16* __restrict__ vT)
{
    const int tb = blockIdx.x;            // 0..127
    const int h  = blockIdx.y;            // 0..11
    const int t  = threadIdx.x;
    const int w  = t >> 6;
    const int l  = t & 63;
    const int l16 = l & 15, lg = l >> 4;
    const int tok0 = tb * 128 + w * 32;   // wave's 32 tokens (same batch)
    const int b  = tok0 >> 10;
    const int s0 = tok0 & 1023;
    const int bh = b * NH + h;

    // A-frags: x hi/lo fp16. lane: row=l16 (token), k=lg*8+j (d). Note this
    // layout is ALSO the valid B-frag layout (col=l16, k=lg*8+j) for V-swap.
    half8 xh[2][2], xl[2][2];
    #pragma unroll
    for (int m = 0; m < 2; ++m)
        #pragma unroll
        for (int kc = 0; kc < 2; ++kc) {
            const float* px = x + (size_t)(tok0 + m * 16 + l16) * ND + h * NDH + kc * 32 + lg * 8;
            const float4 a = *reinterpret_cast<const float4*>(px);
            const float4 c = *reinterpret_cast<const float4*>(px + 4);
            const float vv[8] = {a.x, a.y, a.z, a.w, c.x, c.y, c.z, c.w};
            #pragma unroll
            for (int j = 0; j < 8; ++j) {
                const _Float16 hi = (_Float16)vv[j];
                xh[m][kc][j] = hi;
                xl[m][kc][j] = (_Float16)(vv[j] - (float)hi);
            }
        }

    f32x4 acc[2][4];

    // ---- Q
    #pragma unroll
    for (int m = 0; m < 2; ++m)
        #pragma unroll
        for (int n = 0; n < 4; ++n) acc[m][n] = f32x4{0.f, 0.f, 0.f, 0.f};
    proj_one(Wq, h, l16, lg, xh, xl, acc);
    #pragma unroll
    for (int n = 0; n < 4; ++n) {
        const float bb = bq[h * NDH + n * 16 + l16];
        #pragma unroll
        for (int m = 0; m < 2; ++m)
            #pragma unroll
            for (int r = 0; r < 4; ++r)
                qo[((size_t)bh * NS + s0 + m * 16 + lg * 4 + r) * NDH + n * 16 + l16] =
                    (_Float16)((acc[m][n][r] + bb) * QSCALE);
    }

    // ---- K
    #pragma unroll
    for (int m = 0; m < 2; ++m)
        #pragma unroll
        for (int n = 0; n < 4; ++n) acc[m][n] = f32x4{0.f, 0.f, 0.f, 0.f};
    proj_one(Wk, h, l16, lg, xh, xl, acc);
    #pragma unroll
    for (int n = 0; n < 4; ++n) {
        const float bb = bk[h * NDH + n * 16 + l16];
        #pragma unroll
        for (int m = 0; m < 2; ++m)
            #pragma unroll
            for (int r = 0; r < 4; ++r)
                ko[((size_t)bh * NS + s0 + m * 16 + lg * 4 + r) * NDH + n * 16 + l16] =
                    (_Float16)(acc[m][n][r] + bb);
    }

    // ---- V, swapped: D[d][token] = Wv . x^T  -> writes vT[bh][d][s] with the
    //      same 4x32B-txn store pattern as Q/K (no 2B scatter).
    f32x4 accT[4][2];
    #pragma unroll
    for (int dt = 0; dt < 4; ++dt)
        #pragma unroll
        for (int tt = 0; tt < 2; ++tt) accT[dt][tt] = f32x4{0.f, 0.f, 0.f, 0.f};
    #pragma unroll
    for (int dt = 0; dt < 4; ++dt)
        #pragma unroll
        for (int kc = 0; kc < 2; ++kc) {
            const float* pw = Wv + (size_t)(h * NDH + dt * 16 + l16) * NDH + kc * 32 + lg * 8;
            const float4 a = *reinterpret_cast<const float4*>(pw);
            const float4 b = *reinterpret_cast<const float4*>(pw + 4);
            const float wv[8] = {a.x, a.y, a.z, a.w, b.x, b.y, b.z, b.w};
            half8 wf;
            #pragma unroll
            for (int j = 0; j < 8; ++j) wf[j] = (_Float16)wv[j];
            #pragma unroll
            for (int tt = 0; tt < 2; ++tt) {
                accT[dt][tt] = __builtin_amdgcn_mfma_f32_16x16x32_f16(wf, xh[tt][kc], accT[dt][tt], 0, 0, 0);
                accT[dt][tt] = __builtin_amdgcn_mfma_f32_16x16x32_f16(wf, xl[tt][kc], accT[dt][tt], 0, 0, 0);
            }
        }
    #pragma unroll
    for (int dt = 0; dt < 4; ++dt)
        #pragma unroll
        for (int r = 0; r < 4; ++r) {
            const float bb = bv[h * NDH + dt * 16 + lg * 4 + r];
            #pragma unroll
            for (int tt = 0; tt < 2; ++tt)
                vT[((size_t)bh * NDH + dt * 16 + lg * 4 + r) * NS + s0 + tt * 16 + l16] =
                    (_Float16)(accT[dt][tt][r] + bb);
        }
}

// ---------------------------------------------------------------------------
// Kernel 2: barrier-free MFMA flash attention. Block = 4 INDEPENDENT waves
// (each: 32 q-rows, own PT slice -> no __syncthreads anywhere). KV-tile 64,
// 16 iterations. K/Q/V fragments loaded directly from global (L1/L2-hot).
// Swapped QK^T (S^T = K*Q^T) -> softmax mostly in-lane (2 shfl per stat).
// P crosses lanes via row-XOR-swizzled per-wave LDS (same-wave ordering).
// NOTE: NO min-occupancy arg in launch_bounds — R4's ",4" capped VGPR to 64
// and caused ~1.3 GB/launch of scratch spill (dur 194->428us). Allocator
// needs ~120 VGPR for the fragment set; 120 <= 128 still allows 4 waves/SIMD.
// ---------------------------------------------------------------------------
__global__ __launch_bounds__(256) void flash_mfma(
    const _Float16* __restrict__ q, const _Float16* __restrict__ k,
    const _Float16* __restrict__ vT, float* __restrict__ out)
{
    __shared__ __align__(16) _Float16 PT[4][32 * 64];  // per-wave [q][kv], swizzled

    const int bh = blockIdx.x;            // 0..191; XCD = bh%8 fixed (192%8==0)
    const int qt = blockIdx.y;            // 0..7
    const int t  = threadIdx.x;
    const int w  = t >> 6;
    const int l  = t & 63;
    const int l16 = l & 15, lg = l >> 4;
    const int q0 = qt * 128 + w * 32;

    const size_t qkbase = (size_t)bh * NS * NDH;
    const size_t vtbase = (size_t)bh * NDH * NS;

    // Q B-frags (loop-invariant): lane: col=l16 (q), k=lg*8+j (d)
    half8 qf[2][2];
    #pragma unroll
    for (int n2 = 0; n2 < 2; ++n2)
        #pragma unroll
        for (int kc = 0; kc < 2; ++kc)
            qf[n2][kc] = *reinterpret_cast<const half8*>(
                q + qkbase + (size_t)(q0 + n2 * 16 + l16) * NDH + kc * 32 + lg * 8);

    f32x4 Oacc[2][4];
    #pragma unroll
    for (int m = 0; m < 2; ++m)
        #pragma unroll
        for (int n = 0; n < 4; ++n) Oacc[m][n] = f32x4{0.f, 0.f, 0.f, 0.f};
    float mi[2] = {-INFINITY, -INFINITY};
    float li[2] = {0.f, 0.f};

    // K A-frag prefetch for kt=0: lane: row=l16 (kv), k=lg*8+j (d)
    half8 kf[4][2];
    #pragma unroll
    for (int m4 = 0; m4 < 4; ++m4)
        #pragma unroll
        for (int kc = 0; kc < 2; ++kc)
            kf[m4][kc] = *reinterpret_cast<const half8*>(
                k + qkbase + (size_t)(m4 * 16 + l16) * NDH + kc * 32 + lg * 8);

    for (int kt = 0; kt < 16; ++kt) {
        const int kvb = kt * 64;

        // ---- issue V B-frags early (used after softmax): lane: col=l16 (d), k=lg*8+j (kv)
        half8 vf[4][2];
        #pragma unroll
        for (int n4 = 0; n4 < 4; ++n4)
            #pragma unroll
            for (int kc = 0; kc < 2; ++kc)
                vf[n4][kc] = *reinterpret_cast<const half8*>(
                    vT + vtbase + (size_t)(n4 * 16 + l16) * NS + kvb + kc * 32 + lg * 8);

        // ---- S^T = K * Q^T : st[m4][n2], elem r -> kv = m4*16+lg*4+r, q = n2*16+l16
        f32x4 st[4][2];
        __builtin_amdgcn_s_setprio(1);
        #pragma unroll
        for (int m4 = 0; m4 < 4; ++m4)
            #pragma unroll
            for (int n2 = 0; n2 < 2; ++n2) {
                st[m4][n2] = f32x4{0.f, 0.f, 0.f, 0.f};
                #pragma unroll
                for (int kc = 0; kc < 2; ++kc)
                    st[m4][n2] = __builtin_amdgcn_mfma_f32_16x16x32_f16(
                        kf[m4][kc], qf[n2][kc], st[m4][n2], 0, 0, 0);
            }
        __builtin_amdgcn_s_setprio(0);

        // ---- prefetch K for kt+1 (latency covered by softmax+PV)
        half8 kf2[4][2];
        if (kt < 15) {
            #pragma unroll
            for (int m4 = 0; m4 < 4; ++m4)
                #pragma unroll
                for (int kc = 0; kc < 2; ++kc)
                    kf2[m4][kc] = *reinterpret_cast<const half8*>(
                        k + qkbase + (size_t)(kvb + 64 + m4 * 16 + l16) * NDH + kc * 32 + lg * 8);
        }

        // ---- online softmax in exp2 domain (scale folded into q)
        float cfac[2];
        #pragma unroll
        for (int n2 = 0; n2 < 2; ++n2) {
            float pm = st[0][n2][0];
            #pragma unroll
            for (int m4 = 0; m4 < 4; ++m4)
                #pragma unroll
                for (int r = 0; r < 4; ++r) pm = fmaxf(pm, st[m4][n2][r]);
            pm = fmaxf(pm, __shfl_xor(pm, 16));
            pm = fmaxf(pm, __shfl_xor(pm, 32));
            const float mn = fmaxf(mi[n2], pm);
            cfac[n2] = __builtin_amdgcn_exp2f(mi[n2] - mn);
            mi[n2] = mn;
            float rs = 0.f;
            #pragma unroll
            for (int m4 = 0; m4 < 4; ++m4)
                #pragma unroll
                for (int r = 0; r < 4; ++r) {
                    const float p = __builtin_amdgcn_exp2f(st[m4][n2][r] - mn);
                    st[m4][n2][r] = p;
                    rs += p;
                }
            rs += __shfl_xor(rs, 16);
            rs += __shfl_xor(rs, 32);
            li[n2] = li[n2] * cfac[n2] + rs;
        }

        // ---- rescale Oacc BEFORE adding this tile's PV
        #pragma unroll
        for (int m2 = 0; m2 < 2; ++m2) {
            float cb[4];
            #pragma unroll
            for (int r = 0; r < 4; ++r) cb[r] = __shfl(cfac[m2], lg * 4 + r);
            #pragma unroll
            for (int n4 = 0; n4 < 4; ++n4)
                #pragma unroll
                for (int r = 0; r < 4; ++r) Oacc[m2][n4][r] *= cb[r];
        }

        // ---- P -> per-wave PT (packed fp16, b64 writes, 16B-slot XOR swizzle)
        _Float16* Pw = PT[w];
        #pragma unroll
        for (int n2 = 0; n2 < 2; ++n2) {
            const int row = n2 * 16 + l16;
            #pragma unroll
            for (int m4 = 0; m4 < 4; ++m4) {
                const unsigned int p01 = __builtin_bit_cast(unsigned int,
                    __builtin_amdgcn_cvt_pkrtz(st[m4][n2][0], st[m4][n2][1]));
                const unsigned int p23 = __builtin_bit_cast(unsigned int,
                    __builtin_amdgcn_cvt_pkrtz(st[m4][n2][2], st[m4][n2][3]));
                const int swz = (m4 * 2 + (lg >> 1)) ^ (row & 7);   // 16B slot index
                uint2* dst = reinterpret_cast<uint2*>(&Pw[row * 64 + swz * 8 + (lg & 1) * 4]);
                *dst = uint2{p01, p23};
            }
        }

        // ---- P A-frags: row = m2*16+l16 (q), k = kv = kc*32+lg*8+j
        half8 pf[2][2];
        #pragma unroll
        for (int m2 = 0; m2 < 2; ++m2) {
            const int row = m2 * 16 + l16;
            #pragma unroll
            for (int kc = 0; kc < 2; ++kc) {
                const int swz = (kc * 4 + lg) ^ (row & 7);
                pf[m2][kc] = *reinterpret_cast<const half8*>(&Pw[row * 64 + swz * 8]);
            }
        }

        // ---- PV accumulate
        __builtin_amdgcn_s_setprio(1);
        #pragma unroll
        for (int m2 = 0; m2 < 2; ++m2)
            #pragma unroll
            for (int n4 = 0; n4 < 4; ++n4)
                #pragma unroll
                for (int kc = 0; kc < 2; ++kc)
                    Oacc[m2][n4] = __builtin_amdgcn_mfma_f32_16x16x32_f16(
                        pf[m2][kc], vf[n4][kc], Oacc[m2][n4], 0, 0, 0);
        __builtin_amdgcn_s_setprio(0);

        // rotate prefetched K
        #pragma unroll
        for (int m4 = 0; m4 < 4; ++m4)
            #pragma unroll
            for (int kc = 0; kc < 2; ++kc) kf[m4][kc] = kf2[m4][kc];
    }

    // ---- epilogue
    const int b = bh / NH;
    const int h = bh % NH;
    float inv[2] = {1.f / li[0], 1.f / li[1]};
    #pragma unroll
    for (int m2 = 0; m2 < 2; ++m2)
        #pragma unroll
        for (int r = 0; r < 4; ++r) {
            const float ib = __shfl(inv[m2], lg * 4 + r);
            const int s = q0 + m2 * 16 + lg * 4 + r;
            #pragma unroll
            for (int n4 = 0; n4 < 4; ++n4)
                out[((size_t)b * NS + s) * ND + h * NDH + n4 * 16 + l16] = Oacc[m2][n4][r] * ib;
        }
}

// ---------------------------------------------------------------------------
extern "C" void kernel_launch(void* const* d_in, const int* in_sizes, int n_in,
                              void* d_out, int out_size, void* d_ws, size_t ws_size,
                              hipStream_t stream)
{
    const float* x  = (const float*)d_in[0];
    const float* Wq = (const float*)d_in[1];
    const float* bq = (const float*)d_in[2];
    const float* Wk = (const float*)d_in[3];
    const float* bk = (const float*)d_in[4];
    const float* Wv = (const float*)d_in[5];
    const float* bv = (const float*)d_in[6];
    float* out = (float*)d_out;

    _Float16* qb = (_Float16*)d_ws;
    _Float16* kb = qb + QKV_ELEMS;
    _Float16* vt = kb + QKV_ELEMS;

    dim3 g1(NB * NS / 128, NH);
    qkv_mfma<<<g1, 256, 0, stream>>>(x, Wq, bq, Wk, bk, Wv, bv, qb, kb, vt);

    dim3 g2(NB * NH, 8);   // x = bh (pins each head to one XCD), y = q-tile
    flash_mfma<<<g2, 256, 0, stream>>>(qb, kb, vt, out);
}